// Round 5
// baseline (1142.200 us; speedup 1.0000x reference)
//
#include <hip/hip_runtime.h>
#include <hip/hip_bf16.h>

#define DI __device__ __forceinline__

typedef __attribute__((ext_vector_type(8))) short          s8v;   // 8 x bf16 bit-patterns
typedef __attribute__((ext_vector_type(4))) float          f4v;
typedef __attribute__((ext_vector_type(4))) unsigned short us4v;

DI unsigned short f2bf(float f) {
  unsigned u = __builtin_bit_cast(unsigned, f);
  u += 0x7fffu + ((u >> 16) & 1u);          // round-to-nearest-even
  return (unsigned short)(u >> 16);
}

static constexpr long LDP = 10048;          // padded K-stride for bf16 panels

// ===========================================================================
// Barrier-free all-register tall-skinny GEMM for the Adj passes.
//   part[s] += A[strip rows] @ B^T   (B^T is [BN][K] bf16, ldb-padded)
// One wave = one 16-row strip. A-frag loaded global->VGPR directly
// (f32 path converts to bf16 in-reg and mirrors to a bf16 copy of A).
// B-frags read per K-step from the (L2-resident) B panel. No LDS, no
// __syncthreads: compiler emits counted vmcnt, waves stream independently.
// ===========================================================================
template<int BN, int SPLITK, bool AF32, bool MIRROR>
__global__ __launch_bounds__(256)
void rgemm(const void* __restrict__ Avoid, long lda,
           const unsigned short* __restrict__ Bt, long ldb,
           float* __restrict__ part, long pstride, int ldc,
           int M, int K,
           unsigned short* __restrict__ mirror, long mld)
{
  constexpr int FN = BN / 16;
  const int lane  = threadIdx.x & 63;
  const int strip = blockIdx.x * 4 + (threadIdx.x >> 6);
  const int r0    = strip * 16;
  if (r0 >= M) return;
  const int s = blockIdx.y;

  const int arow = r0 + (lane & 15);        // A row this lane feeds (A-frag: row=lane&15)
  const int ks8  = (lane >> 4) * 8;         // k-slice within the 32-wide K-step

  const int tsteps = (K + 31) >> 5;
  const int base_  = tsteps / SPLITK, rem_ = tsteps % SPLITK;
  const int sbeg   = s * base_ + (s < rem_ ? s : rem_);
  const int send   = sbeg + base_ + (s < rem_ ? 1 : 0);
  const int fullst = K >> 5;
  const int tcap   = send < fullst ? send : fullst;

  const float*          af = (const float*)Avoid + (long)arow * lda + ks8;
  const unsigned short* ah = (const unsigned short*)Avoid + (long)arow * lda + ks8;
  const unsigned short* bp[FN];
  #pragma unroll
  for (int ni = 0; ni < FN; ni++)
    bp[ni] = Bt + (long)(ni * 16 + (lane & 15)) * ldb + ks8;

  f4v acc[FN] = {};

  // double-buffered register state (all statically indexed — no scratch)
  f4v xa0, xa1, ya0, ya1; s8v xah, yah; s8v xb[FN], yb[FN];

  auto LOAD = [&](int t, f4v& a0, f4v& a1, s8v& ahh, s8v* b) {
    const long k0 = (long)t << 5;
    if (AF32) { a0 = *(const f4v*)(af + k0); a1 = *(const f4v*)(af + k0 + 4); }
    else      { ahh = *(const s8v*)(ah + k0); }
    #pragma unroll
    for (int ni = 0; ni < FN; ni++) b[ni] = *(const s8v*)(bp[ni] + k0);
  };

  auto COMP = [&](int t, const f4v& a0, const f4v& a1, const s8v& ahh, const s8v* b) {
    s8v afr;
    if (AF32) {
      #pragma unroll
      for (int i = 0; i < 4; i++) {
        afr[i]     = (short)f2bf(a0[i]);
        afr[4 + i] = (short)f2bf(a1[i]);
      }
      if (MIRROR)
        *(s8v*)(mirror + (long)arow * mld + ((long)t << 5) + ks8) = afr;
    } else {
      afr = ahh;
    }
    #pragma unroll
    for (int ni = 0; ni < FN; ni++)
      acc[ni] = __builtin_amdgcn_mfma_f32_16x16x32_bf16(afr, b[ni], acc[ni], 0, 0, 0);
  };

  // ---- main loop over full 32-wide K-steps, 2-unrolled ping/pong
  int t = sbeg;
  if (t < tcap) LOAD(t, xa0, xa1, xah, xb);
  for (; t + 2 <= tcap; t += 2) {
    LOAD(t + 1, ya0, ya1, yah, yb);
    COMP(t, xa0, xa1, xah, xb);
    if (t + 2 < tcap) LOAD(t + 2, xa0, xa1, xah, xb);
    COMP(t + 1, ya0, ya1, yah, yb);
  }
  if (t < tcap) COMP(t, xa0, xa1, xah, xb);

  // ---- ragged final K-step (16 of 32 valid), owned by the last split
  if (send == tsteps && (K & 31)) {
    const long kt  = (long)fullst << 5;
    const bool oob = (ks8 >= (K - (int)kt));
    s8v afr, b[FN];
    if (AF32) {
      f4v a0 = {0.f, 0.f, 0.f, 0.f}, a1 = {0.f, 0.f, 0.f, 0.f};
      if (!oob) { a0 = *(const f4v*)(af + kt); a1 = *(const f4v*)(af + kt + 4); }
      #pragma unroll
      for (int i = 0; i < 4; i++) {
        afr[i]     = (short)f2bf(a0[i]);
        afr[4 + i] = (short)f2bf(a1[i]);
      }
      if (MIRROR)   // also zero-fills mirror pad cols [K, K+16)
        *(s8v*)(mirror + (long)arow * mld + kt + ks8) = afr;
    } else {
      afr = *(const s8v*)(ah + kt);         // reads zeroed pad for oob slices
    }
    #pragma unroll
    for (int ni = 0; ni < FN; ni++) b[ni] = *(const s8v*)(bp[ni] + kt);
    #pragma unroll
    for (int ni = 0; ni < FN; ni++)
      acc[ni] = __builtin_amdgcn_mfma_f32_16x16x32_bf16(afr, b[ni], acc[ni], 0, 0, 0);
  }

  // ---- epilogue: raw f32 partials (C-frag: col=lane&15, row=(lane>>4)*4+r)
  float* Cp = part + (long)s * pstride
            + (long)(r0 + (lane >> 4) * 4) * ldc + (lane & 15);
  #pragma unroll
  for (int ni = 0; ni < FN; ni++)
    #pragma unroll
    for (int r = 0; r < 4; r++)
      Cp[(long)r * ldc + ni * 16] = acc[ni][r];
}

// out = op(sum of NSUM split-K partials), vectorized
template<int NSUM, bool RELU>
__global__ __launch_bounds__(256)
void reduceS(const float* __restrict__ p, float* __restrict__ out, int n4, long s4) {
  int i = blockIdx.x * 256 + threadIdx.x;
  if (i >= n4) return;
  const f4v* pv = (const f4v*)p;
  f4v v = pv[i];
  #pragma unroll
  for (int k = 1; k < NSUM; k++) v += pv[i + (long)k * s4];
  if (RELU) {
    v[0] = fmaxf(v[0], 0.f); v[1] = fmaxf(v[1], 0.f);
    v[2] = fmaxf(v[2], 0.f); v[3] = fmaxf(v[3], 0.f);
  }
  ((f4v*)out)[i] = v;
}

// ===========================================================================
// LDS-staged GEMM for the small weight GEMMs (K<=512, few steps) — proven.
// ===========================================================================
template<int ROWS>
DI void stage_lds(const unsigned short* __restrict__ src, long ld, int r0, int k0,
                  unsigned short* lds, int tid) {
  constexpr int IT = (ROWS * 128) / 4096;
  #pragma unroll
  for (int i = 0; i < IT; i++) {
    const int o   = (i * 256 + tid) * 16;
    const int row = o >> 7;
    const int kb  = (o & 127) ^ ((row & 7) << 4);
    const char* s = (const char*)(src + (long)(r0 + row) * ld + k0) + kb;
    char* d = (char*)lds + (i * 256 + (tid & ~63)) * 16;
    __builtin_amdgcn_global_load_lds(
        (const __attribute__((address_space(1))) unsigned int*)s,
        (__attribute__((address_space(3))) unsigned int*)d, 16, 0, 0);
  }
}

template<int BN, bool HAS_BIAS, bool DO_RELU, bool OUT_TBF16>
__global__ __launch_bounds__(256)
void gemm_k(const float* __restrict__ A, long lda,
            const unsigned short* __restrict__ Bt, long ldb,
            const float* __restrict__ bias,
            void* __restrict__ C, long ldc,
            int M, int K)
{
  constexpr int BM = 32;
  constexpr int WN = BN / 4;
  constexpr int FN = WN / 16;
  constexpr int FM = 2;

  __shared__ unsigned short As[2][BM * 64];
  __shared__ unsigned short Bs[2][BN * 64];

  const int tid  = threadIdx.x;
  const int lane = tid & 63;
  const int w    = tid >> 6;
  const int lr   = lane & 15;
  const int lq   = lane >> 4;
  const int m0   = blockIdx.x * BM;
  const int nsteps = (K + 63) >> 6;

  f4v acc[FM][FN] = {};

  const int arow = tid >> 3;
  const int as3  = tid & 7;
  int am = m0 + arow; if (am > M - 1) am = M - 1;
  const float* aptr = A + (long)am * lda + as3 * 8;
  const int abyte = arow * 128 + ((as3 * 16) ^ ((arow & 7) << 4));
  float areg[8];

  auto a_issue = [&](int k0) {
    if (k0 + 63 < K) {
      f4v v0 = *(const f4v*)(aptr + k0);
      f4v v1 = *(const f4v*)(aptr + k0 + 4);
      areg[0]=v0[0]; areg[1]=v0[1]; areg[2]=v0[2]; areg[3]=v0[3];
      areg[4]=v1[0]; areg[5]=v1[1]; areg[6]=v1[2]; areg[7]=v1[3];
    } else {
      #pragma unroll
      for (int i = 0; i < 8; i++) {
        int kg = k0 + as3 * 8 + i;
        areg[i] = (kg < K) ? aptr[k0 + i] : 0.f;
      }
    }
  };

  auto a_write = [&](int buf) {
    s8v av;
    #pragma unroll
    for (int i = 0; i < 8; i++) av[i] = (short)f2bf(areg[i]);
    *(s8v*)((char*)&As[buf][0] + abyte) = av;
  };

  auto compute = [&](int buf) {
    #pragma unroll
    for (int kk = 0; kk < 2; kk++) {
      s8v a[FM], b[FN];
      #pragma unroll
      for (int mi = 0; mi < FM; mi++) {
        int row = mi * 16 + lr;
        int off = row * 128 + ((kk * 64 + lq * 16) ^ ((row & 7) << 4));
        a[mi] = *(const s8v*)((const char*)&As[buf][0] + off);
      }
      #pragma unroll
      for (int ni = 0; ni < FN; ni++) {
        int n   = w * WN + ni * 16 + lr;
        int off = n * 128 + ((kk * 64 + lq * 16) ^ ((n & 7) << 4));
        b[ni] = *(const s8v*)((const char*)&Bs[buf][0] + off);
      }
      #pragma unroll
      for (int mi = 0; mi < FM; mi++)
        #pragma unroll
        for (int ni = 0; ni < FN; ni++)
          acc[mi][ni] = __builtin_amdgcn_mfma_f32_16x16x32_bf16(
              a[mi], b[ni], acc[mi][ni], 0, 0, 0);
    }
  };

  a_issue(0);
  stage_lds<BN>(Bt, ldb, 0, 0, &Bs[0][0], tid);
  a_write(0);
  __syncthreads();

  int buf = 0;
  for (int t = 0; t < nsteps; t++) {
    const bool more = (t + 1 < nsteps);
    const int  kn   = (t + 1) << 6;
    if (more) {
      a_issue(kn);
      stage_lds<BN>(Bt, ldb, 0, kn, &Bs[buf ^ 1][0], tid);
    }
    compute(buf);
    if (more) a_write(buf ^ 1);
    __syncthreads();
    buf ^= 1;
  }

  #pragma unroll
  for (int mi = 0; mi < FM; mi++) {
    #pragma unroll
    for (int ni = 0; ni < FN; ni++) {
      const int n  = w * WN + ni * 16 + lr;
      const int mb = m0 + mi * 16 + lq * 4;
      f4v v = acc[mi][ni];
      if (HAS_BIAS) {
        const float bv = bias[n];
        v[0] += bv; v[1] += bv; v[2] += bv; v[3] += bv;
      }
      if (DO_RELU) {
        v[0] = fmaxf(v[0], 0.f); v[1] = fmaxf(v[1], 0.f);
        v[2] = fmaxf(v[2], 0.f); v[3] = fmaxf(v[3], 0.f);
      }
      if (OUT_TBF16) {
        if (mb < M) {
          us4v o;
          o[0] = f2bf(v[0]); o[1] = f2bf(v[1]); o[2] = f2bf(v[2]); o[3] = f2bf(v[3]);
          *(us4v*)((unsigned short*)C + (long)n * ldc + mb) = o;
        }
      } else {
        float* Cf = (float*)C;
        #pragma unroll
        for (int r = 0; r < 4; r++)
          if (mb + r < M) Cf[(long)(mb + r) * ldc + n] = v[r];
      }
    }
  }
}

// zero K-pad [10000,10048) of the P panels (ws re-poisoned 0xAA every launch)
__global__ __launch_bounds__(256)
void padzero(unsigned short* p0, unsigned short* p1, unsigned short* p2) {
  int i = blockIdx.x * 256 + threadIdx.x;
  if (i >= 320 * 12) return;
  int r = i / 12, c = i % 12;
  unsigned short* b;
  if      (r < 128)  b = p0 + (long)r * LDP;
  else if (r < 256)  b = p1 + (long)(r - 128) * LDP;
  else               b = p2 + (long)(r - 256) * LDP;
  us4v z = {0, 0, 0, 0};
  *(us4v*)(b + 10000 + c * 4) = z;
}

// weights f32 -> bf16, row-major [out][k] (already B-form)
__global__ __launch_bounds__(256)
void wconv(const float* __restrict__ w0, const float* __restrict__ w1,
           const float* __restrict__ w2, const float* __restrict__ wp1,
           const float* __restrict__ wp2, unsigned short* __restrict__ out)
{
  int i = blockIdx.x * 256 + threadIdx.x;
  const float* src; int off;
  if      (i < 65536) { src = w0;  off = i; }
  else if (i < 81920) { src = w1;  off = i - 65536; }
  else if (i < 90112) { src = w2;  off = i - 81920; }
  else if (i < 94208) { src = wp1; off = i - 90112; }
  else if (i < 98304) { src = wp2; off = i - 94208; }
  else return;
  out[i] = f2bf(src[off]);
}

// ---------------------------------------------------------------------------
extern "C" void kernel_launch(void* const* d_in, const int* in_sizes, int n_in,
                              void* d_out, int out_size, void* d_ws, size_t ws_size,
                              hipStream_t stream)
{
  const float* x   = (const float*)d_in[0];
  const float* Adj = (const float*)d_in[1];
  const float* W0  = (const float*)d_in[2];
  const float* b0  = (const float*)d_in[3];
  const float* W1  = (const float*)d_in[4];
  const float* b1  = (const float*)d_in[5];
  const float* W2  = (const float*)d_in[6];
  const float* b2  = (const float*)d_in[7];
  const float* Wp1 = (const float*)d_in[8];
  const float* bp1 = (const float*)d_in[9];
  const float* Wp2 = (const float*)d_in[10];
  const float* bp2 = (const float*)d_in[11];

  float* z_out   = (float*)d_out;             // [10000][64]
  float* emb_out = (float*)d_out + 640000;    // [10000][64]

  char* ws = (char*)d_ws;                     // ~273 MB used (ws ~1.6 GB)
  unsigned short* Wb   = (unsigned short*)(ws);
  unsigned short* P0T  = (unsigned short*)(ws + (1L  << 20));  // [128][10048] bf16
  unsigned short* P1T  = (unsigned short*)(ws + (4L  << 20));  // [128][10048] bf16
  unsigned short* P2T  = (unsigned short*)(ws + (7L  << 20));  // [64][10048]  bf16
  float*          H0   = (float*)(ws + (9L  << 20));           // [10000][128] f32
  float*          H1   = (float*)(ws + (15L << 20));           // [10000][128] f32
  float*          Tb   = (float*)(ws + (21L << 20));           // [10000][64]  f32
  float*          part = (float*)(ws + (24L << 20));           // [8][10000][128] f32
  unsigned short* AdjB = (unsigned short*)(ws + (72L << 20));  // [10016][10048] bf16

  dim3 blk(256);
  const int TILES  = 313;                     // old gemm_k: ceil(10000/32)
  const int RBLK   = 157;                     // rgemm: ceil(625 strips / 4 waves)

  padzero<<<dim3(15),  blk, 0, stream>>>(P0T, P1T, P2T);
  wconv  <<<dim3(384), blk, 0, stream>>>(W0, W1, W2, Wp1, Wp2, Wb);

  // P0^T = (x @ W0^T + b0)^T   bf16 [128][LDP]
  gemm_k<128,true ,false,true ><<<dim3(TILES), blk, 0, stream>>>(
      x, 512, Wb, 512, b0, P0T, LDP, 10000, 512);
  // part[s] = Adj @ P0 (f32 A, split-K=8, mirrors Adj->bf16; barrier-free)
  rgemm<128,8,true ,true ><<<dim3(RBLK,8), blk, 0, stream>>>(
      Adj, 10000, P0T, LDP, part, 1280000, 128, 10000, 10000, AdjB, LDP);
  // H0 = relu(sum part)
  reduceS<8,true ><<<dim3(1250), blk, 0, stream>>>(part, H0, 320000, 320000);
  // P1^T = (H0 @ W1^T + b1)^T
  gemm_k<128,true ,false,true ><<<dim3(TILES), blk, 0, stream>>>(
      H0, 128, Wb + 65536, 128, b1, P1T, LDP, 10000, 128);
  // part[s] = AdjB @ P1 (bf16 A, barrier-free)
  rgemm<128,8,false,false><<<dim3(RBLK,8), blk, 0, stream>>>(
      AdjB, LDP, P1T, LDP, part, 1280000, 128, 10000, 10000, nullptr, 0);
  // H1 = relu(sum part)
  reduceS<8,true ><<<dim3(1250), blk, 0, stream>>>(part, H1, 320000, 320000);
  // P2^T = (H1 @ W2^T + b2)^T   bf16 [64][LDP]
  gemm_k<64 ,true ,false,true ><<<dim3(TILES), blk, 0, stream>>>(
      H1, 128, Wb + 81920, 128, b2, P2T, LDP, 10000, 128);
  // part[s] = AdjB @ P2 (barrier-free)
  rgemm<64 ,8,false,false><<<dim3(RBLK,8), blk, 0, stream>>>(
      AdjB, LDP, P2T, LDP, part, 640000, 64, 10000, 10000, nullptr, 0);
  // emb = sum part -> d_out second half
  reduceS<8,false><<<dim3(625), blk, 0, stream>>>(part, emb_out, 160000, 160000);
  // T = relu(emb @ Wp1^T + bp1)
  gemm_k<64 ,true ,true ,false><<<dim3(TILES), blk, 0, stream>>>(
      emb_out, 64, Wb + 90112, 64, bp1, Tb, 64, 10000, 64);
  // z = T @ Wp2^T + bp2 -> d_out first half
  gemm_k<64 ,true ,false,false><<<dim3(TILES), blk, 0, stream>>>(
      Tb, 64, Wb + 94208, 64, bp2, z_out, 64, 10000, 64);
}

// Round 7
// 1050.859 us; speedup vs baseline: 1.0869x; 1.0869x over previous
//
#include <hip/hip_runtime.h>
#include <hip/hip_bf16.h>

#define DI __device__ __forceinline__

typedef __attribute__((ext_vector_type(8))) short          s8v;   // 8 x bf16 bit-patterns
typedef __attribute__((ext_vector_type(4))) float          f4v;
typedef __attribute__((ext_vector_type(4))) unsigned short us4v;

DI unsigned short f2bf(float f) {
  unsigned u = __builtin_bit_cast(unsigned, f);
  u += 0x7fffu + ((u >> 16) & 1u);          // round-to-nearest-even
  return (unsigned short)(u >> 16);
}

static constexpr long LDP = 10048;          // padded K-stride for bf16 panels

// ===========================================================================
// Adj pass GEMM:  part[s] = A[32-row tile] @ B^T   (both bf16, LDP-padded)
// BM=32, BK=32, 4 waves, 20KB LDS -> 8 blocks/CU (32 waves/CU).
// LDS layout [4 kslice][rows][16B]: global_load_lds-linear on write,
// lane-consecutive 16B on ds_read_b128 -> zero bank conflicts, zero VALU
// repack. 2-phase double buffer; latency hidden by 8 co-resident blocks.
// ===========================================================================
template<int BN, int SPLITK>
__global__ __launch_bounds__(256)
void adj_gemm(const unsigned short* __restrict__ A,   // [>=M+pad rows][LDP]
              const unsigned short* __restrict__ Bt,  // [BN][LDP]
              float* __restrict__ part, long pstride, int ldc,
              int M, int tsteps)                      // tsteps: 32-wide K-steps
{
  constexpr int BM = 32;
  constexpr int WN = BN / 4;                // per-wave col span (32 or 16)
  constexpr int FN = WN / 16;               // 2 (BN=128) or 1 (BN=64)
  constexpr int FM = 2;

  __shared__ unsigned short As[2][BM * 32];  // 2 KB per buf
  __shared__ unsigned short Bs[2][BN * 32];  // 8/4 KB per buf

  const int tid  = threadIdx.x;
  const int lane = tid & 63;
  const int w    = tid >> 6;
  const int lr   = lane & 15;
  const int lq   = lane >> 4;
  const int m0   = blockIdx.x * BM;
  const int s    = blockIdx.y;

  const int base_ = tsteps / SPLITK, rem_ = tsteps % SPLITK;
  const int sbeg  = s * base_ + (s < rem_ ? s : rem_);
  const int send  = sbeg + base_ + (s < rem_ ? 1 : 0);
  const int nst   = send - sbeg;

  f4v acc[FM][FN] = {};

  auto stage = [&](int t, int buf) {
    const int k0 = t << 5;
    if (tid < 128) {                         // A tile: 2048 B = 128 x 16B chunks
      const int o   = tid * 16;
      const int ks  = o >> 9;                // / (32 rows * 16B)
      const int row = (o >> 4) & 31;
      const unsigned short* src = A + (long)(m0 + row) * LDP + k0 + ks * 8;
      __builtin_amdgcn_global_load_lds(
          (const __attribute__((address_space(1))) unsigned int*)src,
          (__attribute__((address_space(3))) unsigned int*)
              ((char*)&As[buf][0] + (tid & ~63) * 16), 16, 0, 0);
    }
    constexpr int BIT = (BN * 64) / 4096;    // B tile: BN*64 B
    #pragma unroll
    for (int i = 0; i < BIT; i++) {
      const int o  = (i * 256 + tid) * 16;
      const int ks = o / (BN * 16);
      const int n  = (o >> 4) & (BN - 1);
      const unsigned short* src = Bt + (long)n * LDP + k0 + ks * 8;
      __builtin_amdgcn_global_load_lds(
          (const __attribute__((address_space(1))) unsigned int*)src,
          (__attribute__((address_space(3))) unsigned int*)
              ((char*)&Bs[buf][0] + (i * 256 + (tid & ~63)) * 16), 16, 0, 0);
    }
  };

  auto compute = [&](int buf) {
    s8v a[FM], b[FN];
    #pragma unroll
    for (int mi = 0; mi < FM; mi++)          // lanes 0-15 consecutive 16B: no conflict
      a[mi] = *(const s8v*)((const char*)&As[buf][0]
                            + lq * (BM * 16) + (mi * 16 + lr) * 16);
    #pragma unroll
    for (int ni = 0; ni < FN; ni++)
      b[ni] = *(const s8v*)((const char*)&Bs[buf][0]
                            + lq * (BN * 16) + (w * WN + ni * 16 + lr) * 16);
    #pragma unroll
    for (int mi = 0; mi < FM; mi++)
      #pragma unroll
      for (int ni = 0; ni < FN; ni++)
        acc[mi][ni] = __builtin_amdgcn_mfma_f32_16x16x32_bf16(
            a[mi], b[ni], acc[mi][ni], 0, 0, 0);
  };

  stage(sbeg, 0);
  __syncthreads();
  int buf = 0;
  for (int t = 0; t < nst; t++) {
    if (t + 1 < nst) stage(sbeg + t + 1, buf ^ 1);   // issue BEFORE compute
    compute(buf);
    __syncthreads();
    buf ^= 1;
  }

  // epilogue: raw f32 partials (C-frag: col=lane&15, row=(lane>>4)*4+r)
  float* Cp = part + (long)s * pstride;
  #pragma unroll
  for (int mi = 0; mi < FM; mi++)
    #pragma unroll
    for (int ni = 0; ni < FN; ni++) {
      const int row = m0 + mi * 16 + lq * 4;
      const int col = w * WN + ni * 16 + lr;
      #pragma unroll
      for (int r = 0; r < 4; r++)
        if (row + r < M) Cp[(long)(row + r) * ldc + col] = acc[mi][ni][r];
    }
}

// Adj f32 -> bf16 copy with zeroed K-pad [10000,10016). One block per row.
__global__ __launch_bounds__(256)
void adjconv(const float* __restrict__ Adj, unsigned short* __restrict__ out) {
  const long row = blockIdx.x;
  const float* src = Adj + row * 10000L;
  unsigned short* dst = out + row * LDP;
  for (int c8 = threadIdx.x; c8 < 1252; c8 += 256) {
    const int c = c8 * 8;
    s8v v;
    if (c + 8 <= 10000) {
      f4v a = *(const f4v*)(src + c);
      f4v b = *(const f4v*)(src + c + 4);
      #pragma unroll
      for (int i = 0; i < 4; i++) {
        v[i]     = (short)f2bf(a[i]);
        v[4 + i] = (short)f2bf(b[i]);
      }
    } else {
      #pragma unroll
      for (int i = 0; i < 8; i++)
        v[i] = (c + i < 10000) ? (short)f2bf(src[c + i]) : (short)0;
    }
    *(s8v*)(dst + c) = v;
  }
}

// out = op(sum of NSUM split-K partials), vectorized
template<int NSUM, bool RELU>
__global__ __launch_bounds__(256)
void reduceS(const float* __restrict__ p, float* __restrict__ out, int n4, long s4) {
  int i = blockIdx.x * 256 + threadIdx.x;
  if (i >= n4) return;
  const f4v* pv = (const f4v*)p;
  f4v v = pv[i];
  #pragma unroll
  for (int k = 1; k < NSUM; k++) v += pv[i + (long)k * s4];
  if (RELU) {
    v[0] = fmaxf(v[0], 0.f); v[1] = fmaxf(v[1], 0.f);
    v[2] = fmaxf(v[2], 0.f); v[3] = fmaxf(v[3], 0.f);
  }
  ((f4v*)out)[i] = v;
}

// ===========================================================================
// LDS-staged GEMM for the small weight GEMMs (K<=512) — proven in round 3.
// ===========================================================================
template<int ROWS>
DI void stage_lds(const unsigned short* __restrict__ src, long ld, int r0, int k0,
                  unsigned short* lds, int tid) {
  constexpr int IT = (ROWS * 128) / 4096;
  #pragma unroll
  for (int i = 0; i < IT; i++) {
    const int o   = (i * 256 + tid) * 16;
    const int row = o >> 7;
    const int kb  = (o & 127) ^ ((row & 7) << 4);
    const char* s = (const char*)(src + (long)(r0 + row) * ld + k0) + kb;
    char* d = (char*)lds + (i * 256 + (tid & ~63)) * 16;
    __builtin_amdgcn_global_load_lds(
        (const __attribute__((address_space(1))) unsigned int*)s,
        (__attribute__((address_space(3))) unsigned int*)d, 16, 0, 0);
  }
}

template<int BN, bool HAS_BIAS, bool DO_RELU, bool OUT_TBF16>
__global__ __launch_bounds__(256)
void gemm_k(const float* __restrict__ A, long lda,
            const unsigned short* __restrict__ Bt, long ldb,
            const float* __restrict__ bias,
            void* __restrict__ C, long ldc,
            int M, int K)
{
  constexpr int BM = 32;
  constexpr int WN = BN / 4;
  constexpr int FN = WN / 16;
  constexpr int FM = 2;

  __shared__ unsigned short As[2][BM * 64];
  __shared__ unsigned short Bs[2][BN * 64];

  const int tid  = threadIdx.x;
  const int lane = tid & 63;
  const int w    = tid >> 6;
  const int lr   = lane & 15;
  const int lq   = lane >> 4;
  const int m0   = blockIdx.x * BM;
  const int nsteps = (K + 63) >> 6;

  f4v acc[FM][FN] = {};

  const int arow = tid >> 3;
  const int as3  = tid & 7;
  int am = m0 + arow; if (am > M - 1) am = M - 1;
  const float* aptr = A + (long)am * lda + as3 * 8;
  const int abyte = arow * 128 + ((as3 * 16) ^ ((arow & 7) << 4));
  float areg[8];

  auto a_issue = [&](int k0) {
    if (k0 + 63 < K) {
      f4v v0 = *(const f4v*)(aptr + k0);
      f4v v1 = *(const f4v*)(aptr + k0 + 4);
      areg[0]=v0[0]; areg[1]=v0[1]; areg[2]=v0[2]; areg[3]=v0[3];
      areg[4]=v1[0]; areg[5]=v1[1]; areg[6]=v1[2]; areg[7]=v1[3];
    } else {
      #pragma unroll
      for (int i = 0; i < 8; i++) {
        int kg = k0 + as3 * 8 + i;
        areg[i] = (kg < K) ? aptr[k0 + i] : 0.f;
      }
    }
  };

  auto a_write = [&](int buf) {
    s8v av;
    #pragma unroll
    for (int i = 0; i < 8; i++) av[i] = (short)f2bf(areg[i]);
    *(s8v*)((char*)&As[buf][0] + abyte) = av;
  };

  auto compute = [&](int buf) {
    #pragma unroll
    for (int kk = 0; kk < 2; kk++) {
      s8v a[FM], b[FN];
      #pragma unroll
      for (int mi = 0; mi < FM; mi++) {
        int row = mi * 16 + lr;
        int off = row * 128 + ((kk * 64 + lq * 16) ^ ((row & 7) << 4));
        a[mi] = *(const s8v*)((const char*)&As[buf][0] + off);
      }
      #pragma unroll
      for (int ni = 0; ni < FN; ni++) {
        int n   = w * WN + ni * 16 + lr;
        int off = n * 128 + ((kk * 64 + lq * 16) ^ ((n & 7) << 4));
        b[ni] = *(const s8v*)((const char*)&Bs[buf][0] + off);
      }
      #pragma unroll
      for (int mi = 0; mi < FM; mi++)
        #pragma unroll
        for (int ni = 0; ni < FN; ni++)
          acc[mi][ni] = __builtin_amdgcn_mfma_f32_16x16x32_bf16(
              a[mi], b[ni], acc[mi][ni], 0, 0, 0);
    }
  };

  a_issue(0);
  stage_lds<BN>(Bt, ldb, 0, 0, &Bs[0][0], tid);
  a_write(0);
  __syncthreads();

  int buf = 0;
  for (int t = 0; t < nsteps; t++) {
    const bool more = (t + 1 < nsteps);
    const int  kn   = (t + 1) << 6;
    if (more) {
      a_issue(kn);
      stage_lds<BN>(Bt, ldb, 0, kn, &Bs[buf ^ 1][0], tid);
    }
    compute(buf);
    if (more) a_write(buf ^ 1);
    __syncthreads();
    buf ^= 1;
  }

  #pragma unroll
  for (int mi = 0; mi < FM; mi++) {
    #pragma unroll
    for (int ni = 0; ni < FN; ni++) {
      const int n  = w * WN + ni * 16 + lr;
      const int mb = m0 + mi * 16 + lq * 4;
      f4v v = acc[mi][ni];
      if (HAS_BIAS) {
        const float bv = bias[n];
        v[0] += bv; v[1] += bv; v[2] += bv; v[3] += bv;
      }
      if (DO_RELU) {
        v[0] = fmaxf(v[0], 0.f); v[1] = fmaxf(v[1], 0.f);
        v[2] = fmaxf(v[2], 0.f); v[3] = fmaxf(v[3], 0.f);
      }
      if (OUT_TBF16) {
        if (mb < M) {
          us4v o;
          o[0] = f2bf(v[0]); o[1] = f2bf(v[1]); o[2] = f2bf(v[2]); o[3] = f2bf(v[3]);
          *(us4v*)((unsigned short*)C + (long)n * ldc + mb) = o;
        }
      } else {
        float* Cf = (float*)C;
        #pragma unroll
        for (int r = 0; r < 4; r++)
          if (mb + r < M) Cf[(long)(mb + r) * ldc + n] = v[r];
      }
    }
  }
}

// zero K-pad [10000,10048) of the P panels (ws re-poisoned 0xAA every launch)
__global__ __launch_bounds__(256)
void padzero(unsigned short* p0, unsigned short* p1, unsigned short* p2) {
  int i = blockIdx.x * 256 + threadIdx.x;
  if (i >= 320 * 12) return;
  int r = i / 12, c = i % 12;
  unsigned short* b;
  if      (r < 128)  b = p0 + (long)r * LDP;
  else if (r < 256)  b = p1 + (long)(r - 128) * LDP;
  else               b = p2 + (long)(r - 256) * LDP;
  us4v z = {0, 0, 0, 0};
  *(us4v*)(b + 10000 + c * 4) = z;
}

// weights f32 -> bf16, row-major [out][k] (already B-form)
__global__ __launch_bounds__(256)
void wconv(const float* __restrict__ w0, const float* __restrict__ w1,
           const float* __restrict__ w2, const float* __restrict__ wp1,
           const float* __restrict__ wp2, unsigned short* __restrict__ out)
{
  int i = blockIdx.x * 256 + threadIdx.x;
  const float* src; int off;
  if      (i < 65536) { src = w0;  off = i; }
  else if (i < 81920) { src = w1;  off = i - 65536; }
  else if (i < 90112) { src = w2;  off = i - 81920; }
  else if (i < 94208) { src = wp1; off = i - 90112; }
  else if (i < 98304) { src = wp2; off = i - 94208; }
  else return;
  out[i] = f2bf(src[off]);
}

// ---------------------------------------------------------------------------
extern "C" void kernel_launch(void* const* d_in, const int* in_sizes, int n_in,
                              void* d_out, int out_size, void* d_ws, size_t ws_size,
                              hipStream_t stream)
{
  const float* x   = (const float*)d_in[0];
  const float* Adj = (const float*)d_in[1];
  const float* W0  = (const float*)d_in[2];
  const float* b0  = (const float*)d_in[3];
  const float* W1  = (const float*)d_in[4];
  const float* b1  = (const float*)d_in[5];
  const float* W2  = (const float*)d_in[6];
  const float* b2  = (const float*)d_in[7];
  const float* Wp1 = (const float*)d_in[8];
  const float* bp1 = (const float*)d_in[9];
  const float* Wp2 = (const float*)d_in[10];
  const float* bp2 = (const float*)d_in[11];

  float* z_out   = (float*)d_out;             // [10000][64]
  float* emb_out = (float*)d_out + 640000;    // [10000][64]

  char* ws = (char*)d_ws;                     // ~273 MB used (ws ~1.6 GB)
  unsigned short* Wb   = (unsigned short*)(ws);
  unsigned short* P0T  = (unsigned short*)(ws + (1L  << 20));  // [128][10048] bf16
  unsigned short* P1T  = (unsigned short*)(ws + (4L  << 20));  // [128][10048] bf16
  unsigned short* P2T  = (unsigned short*)(ws + (7L  << 20));  // [64][10048]  bf16
  float*          H0   = (float*)(ws + (9L  << 20));           // [10000][128] f32
  float*          H1   = (float*)(ws + (15L << 20));           // [10000][128] f32
  float*          Tb   = (float*)(ws + (21L << 20));           // [10000][64]  f32
  float*          part = (float*)(ws + (24L << 20));           // [8][10000][128] f32
  unsigned short* AdjB = (unsigned short*)(ws + (72L << 20));  // [10016][10048] bf16

  dim3 blk(256);
  const int TILES  = 313;                     // ceil(10000/32)
  const int KSTEPS = 313;                     // 32-wide K-steps over padded 10016

  padzero<<<dim3(15),    blk, 0, stream>>>(P0T, P1T, P2T);
  wconv  <<<dim3(384),   blk, 0, stream>>>(W0, W1, W2, Wp1, Wp2, Wb);
  adjconv<<<dim3(10000), blk, 0, stream>>>(Adj, AdjB);

  // P0^T = (x @ W0^T + b0)^T   bf16 [128][LDP]
  gemm_k<128,true ,false,true ><<<dim3(TILES), blk, 0, stream>>>(
      x, 512, Wb, 512, b0, P0T, LDP, 10000, 512);
  // part[s] = AdjB @ P0  (split-K=8, 8 blocks/CU, conflict-free LDS)
  adj_gemm<128,8><<<dim3(TILES,8), blk, 0, stream>>>(
      AdjB, P0T, part, 1280000, 128, 10000, KSTEPS);
  // H0 = relu(sum part)
  reduceS<8,true ><<<dim3(1250), blk, 0, stream>>>(part, H0, 320000, 320000);
  // P1^T = (H0 @ W1^T + b1)^T
  gemm_k<128,true ,false,true ><<<dim3(TILES), blk, 0, stream>>>(
      H0, 128, Wb + 65536, 128, b1, P1T, LDP, 10000, 128);
  // part[s] = AdjB @ P1
  adj_gemm<128,8><<<dim3(TILES,8), blk, 0, stream>>>(
      AdjB, P1T, part, 1280000, 128, 10000, KSTEPS);
  // H1 = relu(sum part)
  reduceS<8,true ><<<dim3(1250), blk, 0, stream>>>(part, H1, 320000, 320000);
  // P2^T = (H1 @ W2^T + b2)^T   bf16 [64][LDP]
  gemm_k<64 ,true ,false,true ><<<dim3(TILES), blk, 0, stream>>>(
      H1, 128, Wb + 81920, 128, b2, P2T, LDP, 10000, 128);
  // part[s] = AdjB @ P2
  adj_gemm<64 ,8><<<dim3(TILES,8), blk, 0, stream>>>(
      AdjB, P2T, part, 640000, 64, 10000, KSTEPS);
  // emb = sum part -> d_out second half
  reduceS<8,false><<<dim3(625), blk, 0, stream>>>(part, emb_out, 160000, 160000);
  // T = relu(emb @ Wp1^T + bp1)
  gemm_k<64 ,true ,true ,false><<<dim3(TILES), blk, 0, stream>>>(
      emb_out, 64, Wb + 90112, 64, bp1, Tb, 64, 10000, 64);
  // z = T @ Wp2^T + bp2 -> d_out first half
  gemm_k<64 ,true ,false,false><<<dim3(TILES), blk, 0, stream>>>(
      Tb, 64, Wb + 94208, 64, bp2, z_out, 64, 10000, 64);
}